// Round 13
// baseline (264.232 us; speedup 1.0000x reference)
//
#include <hip/hip_runtime.h>
#include <hip/hip_bf16.h>
#include <math.h>

#define N_NODES 50000
#define E_EDGES 1200000
#define E_TOT   (E_EDGES + N_NODES)
#define NEG_SLOPE 0.2f
#define BN_EPS 1e-5f
#define P_PART 196          // partitions of 256 nodes (dst >> 8)
#define B1 256              // blocks in hist/scatter passes
#define NSCAN (P_PART * B1) // 50176

// wave-uniform lane broadcasts via v_readlane (SGPR path, no LDS/bpermute)
__device__ __forceinline__ int rl_i(int v, int l) {
    return __builtin_amdgcn_readlane(v, l);
}
__device__ __forceinline__ float rl_f(float v, int l) {
    return __uint_as_float(__builtin_amdgcn_readlane(__float_as_uint(v), l));
}

// ==================== atomic-free CSR build (partition sort) =============
__global__ void hist_kernel(const int* __restrict__ edst, unsigned* __restrict__ Ghist) {
    __shared__ unsigned hist[P_PART];
    for (int i = threadIdx.x; i < P_PART; i += 256) hist[i] = 0;
    __syncthreads();
    const int chunk = (E_TOT + B1 - 1) / B1;
    const int beg = blockIdx.x * chunk;
    const int end = min(beg + chunk, E_TOT);
    for (int i = beg + threadIdx.x; i < end; i += 256) {
        int d = (i < E_EDGES) ? edst[i] : (i - E_EDGES);
        atomicAdd(&hist[d >> 8], 1u);          // LDS atomic
    }
    __syncthreads();
    for (int p = threadIdx.x; p < P_PART; p += 256)
        Ghist[p * B1 + blockIdx.x] = hist[p];  // bin-major for scan
}

__global__ void scan2_kernel(const unsigned* __restrict__ Ghist, unsigned* __restrict__ Goff) {
    __shared__ unsigned lds[1024];
    const int t = threadIdx.x;
    const int C = (NSCAN + 1023) / 1024;
    const int beg = t * C;
    const int end = min(beg + C, NSCAN);
    unsigned sum = 0;
    for (int i = beg; i < end; ++i) sum += Ghist[i];
    lds[t] = sum;
    __syncthreads();
    for (int off = 1; off < 1024; off <<= 1) {
        unsigned x = (t >= off) ? lds[t - off] : 0;
        __syncthreads();
        lds[t] += x;
        __syncthreads();
    }
    unsigned run = (t == 0) ? 0 : lds[t - 1];
    for (int i = beg; i < end; ++i) { Goff[i] = run; run += Ghist[i]; }
}

__global__ void partbase_kernel(const unsigned* __restrict__ Goff,
                                int* __restrict__ partbase, int* __restrict__ ptr) {
    int p = threadIdx.x;
    if (p < P_PART) partbase[p] = (int)Goff[p * B1];
    if (p == P_PART) partbase[P_PART] = E_TOT;
    if (p == 0) ptr[N_NODES] = E_TOT;
}

__global__ void scat2_kernel(const int* __restrict__ esrc, const int* __restrict__ edst,
                             const unsigned* __restrict__ Goff, unsigned* __restrict__ Gpart) {
    __shared__ unsigned cur[P_PART];
    for (int p = threadIdx.x; p < P_PART; p += 256) cur[p] = Goff[p * B1 + blockIdx.x];
    __syncthreads();
    const int chunk = (E_TOT + B1 - 1) / B1;
    const int beg = blockIdx.x * chunk;
    const int end = min(beg + chunk, E_TOT);
    for (int i = beg + threadIdx.x; i < end; i += 256) {
        int s = (i < E_EDGES) ? esrc[i] : (i - E_EDGES);
        int d = (i < E_EDGES) ? edst[i] : (i - E_EDGES);
        unsigned slot = atomicAdd(&cur[d >> 8], 1u);   // LDS atomic
        Gpart[slot] = ((unsigned)(d & 255) << 16) | (unsigned)s;
    }
}

__global__ void csr_kernel(const int* __restrict__ partbase, const unsigned* __restrict__ Gpart,
                           int* __restrict__ ptr, unsigned short* __restrict__ csr) {
    __shared__ unsigned deg[256];
    __shared__ unsigned scn[256];
    const int p = blockIdx.x;
    const int t = threadIdx.x;
    const int base = partbase[p];
    const int cnt = partbase[p + 1] - base;
    deg[t] = 0;
    __syncthreads();
    for (int i = t; i < cnt; i += 256)
        atomicAdd(&deg[Gpart[base + i] >> 16], 1u);
    __syncthreads();
    unsigned v = deg[t];
    scn[t] = v;
    __syncthreads();
    for (int o = 1; o < 256; o <<= 1) {
        unsigned x = (t >= o) ? scn[t - o] : 0;
        __syncthreads();
        scn[t] += x;
        __syncthreads();
    }
    unsigned excl = scn[t] - v;           // exclusive prefix
    int node = p * 256 + t;
    if (node < N_NODES) ptr[node] = base + (int)excl;
    __syncthreads();
    deg[t] = excl;                        // reuse deg[] as cursor
    __syncthreads();
    for (int i = t; i < cnt; i += 256) {
        unsigned rec = Gpart[base + i];
        unsigned slot = atomicAdd(&deg[rec >> 16], 1u);   // LDS atomic
        csr[base + slot] = (unsigned short)(rec & 0xFFFFu);
    }
}

// ==================== h = x @ W  (+ attention coefficients) ==============
template<int K>
__global__ void lin_att_kernel(const float* __restrict__ x,
                               const float* __restrict__ W,
                               const float* __restrict__ a_s,
                               const float* __restrict__ a_d,
                               __hip_bfloat16* __restrict__ h,
                               float* __restrict__ asrc,
                               float* __restrict__ adst,
                               int n) {
    __shared__ float sW[K * 64];
    const int tid = threadIdx.x, lane = tid & 63;
    for (int i = tid; i < K * 64; i += 256) sW[i] = W[i];
    __syncthreads();
    const float a_sv = a_s[lane];
    const float a_dv = a_d[lane];
    const int wid = blockIdx.x * 4 + (tid >> 6);
    const int nwaves = gridDim.x * 4;
    for (int node = wid; node < n; node += nwaves) {
        float xr[K / 64];
        #pragma unroll
        for (int p = 0; p < K / 64; ++p) xr[p] = x[node * K + p * 64 + lane];
        float acc = 0.f;
        #pragma unroll
        for (int p = 0; p < K / 64; ++p) {
            #pragma unroll
            for (int k = 0; k < 64; ++k) {
                float xk = rl_f(xr[p], k);
                acc = fmaf(xk, sW[(p * 64 + k) * 64 + lane], acc);
            }
        }
        h[node * 64 + lane] = __float2bfloat16(acc);
        float ps = acc * a_sv, pd = acc * a_dv;
        #pragma unroll
        for (int m = 1; m < 32; m <<= 1) {
            ps += __shfl_xor(ps, m, 64);
            pd += __shfl_xor(pd, m, 64);
        }
        if ((lane & 31) == 0) {
            asrc[node * 2 + (lane >> 5)] = ps;
            adst[node * 2 + (lane >> 5)] = pd;
        }
    }
}

// ==================== fused GAT aggregate (no-max softmax) ===============
// one wave per dst node; lane = channel (lanes 0-31 head0, 32-63 head1).
// e is bounded (|e| ~ 5 << 88) so exp() needs no max subtraction:
// alpha = exp(e)/sum(exp(e)) exactly. Denominator accumulated per-lane
// (each lane owns its chunk-slot edges), reduced ONCE per node at the end
// -- removes both per-chunk shfl butterflies and the rescale chain.
template<bool BN, bool FINAL>
__global__ void gat_agg_kernel(const int* __restrict__ ptr,
                               const unsigned short* __restrict__ csr_src,
                               const __hip_bfloat16* __restrict__ h,
                               const float2* __restrict__ asrc, const float2* __restrict__ adst,
                               const float* __restrict__ bias,
                               const float* __restrict__ gamma, const float* __restrict__ beta,
                               const float* __restrict__ mean, const float* __restrict__ var,
                               float* __restrict__ out,
                               const float* __restrict__ x1, const float* __restrict__ Wf,
                               const float* __restrict__ bf, float* __restrict__ out40) {
    __shared__ float sWf[FINAL ? 64 * 40 : 1];
    if constexpr (FINAL) {
        for (int i = threadIdx.x; i < 64 * 40; i += 256) sWf[i] = Wf[i];
        __syncthreads();
    }
    int node = blockIdx.x * 4 + (threadIdx.x >> 6);
    if (node >= N_NODES) return;
    const int lane = threadIdx.x & 63;
    const int half = lane & 31;
    float2 ad = adst[node];
    const float adh = (lane < 32) ? ad.x : ad.y;
    float s_acc = 0.f, acc = 0.f;
    const int beg = ptr[node], end = ptr[node + 1];
    for (int base = beg; base < end; base += 32) {
        const int cnt = min(32, end - base);
        int src = 0; float w = 0.f;
        if (half < cnt) {
            src = (int)csr_src[base + half];
            float2 a2 = asrc[src];
            float ev = ((lane < 32) ? a2.x : a2.y) + adh;
            ev = ev > 0.f ? ev : NEG_SLOPE * ev;
            w = __expf(ev);
        }
        s_acc += w;
        int j = 0;
        for (; j + 8 <= cnt; j += 8) {
            int s0 = rl_i(src, j);
            int s1 = rl_i(src, j + 1);
            int s2 = rl_i(src, j + 2);
            int s3 = rl_i(src, j + 3);
            int s4 = rl_i(src, j + 4);
            int s5 = rl_i(src, j + 5);
            int s6 = rl_i(src, j + 6);
            int s7 = rl_i(src, j + 7);
            float w0 = (lane < 32) ? rl_f(w, j)     : rl_f(w, j + 32);
            float w1 = (lane < 32) ? rl_f(w, j + 1) : rl_f(w, j + 33);
            float w2 = (lane < 32) ? rl_f(w, j + 2) : rl_f(w, j + 34);
            float w3 = (lane < 32) ? rl_f(w, j + 3) : rl_f(w, j + 35);
            float w4 = (lane < 32) ? rl_f(w, j + 4) : rl_f(w, j + 36);
            float w5 = (lane < 32) ? rl_f(w, j + 5) : rl_f(w, j + 37);
            float w6 = (lane < 32) ? rl_f(w, j + 6) : rl_f(w, j + 38);
            float w7 = (lane < 32) ? rl_f(w, j + 7) : rl_f(w, j + 39);
            float h0 = __bfloat162float(h[s0 * 64 + lane]);
            float h1 = __bfloat162float(h[s1 * 64 + lane]);
            float h2 = __bfloat162float(h[s2 * 64 + lane]);
            float h3 = __bfloat162float(h[s3 * 64 + lane]);
            float h4 = __bfloat162float(h[s4 * 64 + lane]);
            float h5 = __bfloat162float(h[s5 * 64 + lane]);
            float h6 = __bfloat162float(h[s6 * 64 + lane]);
            float h7 = __bfloat162float(h[s7 * 64 + lane]);
            acc = fmaf(w0, h0, acc);
            acc = fmaf(w1, h1, acc);
            acc = fmaf(w2, h2, acc);
            acc = fmaf(w3, h3, acc);
            acc = fmaf(w4, h4, acc);
            acc = fmaf(w5, h5, acc);
            acc = fmaf(w6, h6, acc);
            acc = fmaf(w7, h7, acc);
        }
        for (; j < cnt; ++j) {
            int sj = rl_i(src, j);
            float wj = (lane < 32) ? rl_f(w, j) : rl_f(w, j + 32);
            acc = fmaf(wj, __bfloat162float(h[sj * 64 + lane]), acc);
        }
    }
    // one denominator reduction per node (xor<32 stays within each half)
    float s = s_acc;
    #pragma unroll
    for (int o = 1; o < 32; o <<= 1) s += __shfl_xor(s, o, 64);
    float v = acc / (s + 1e-16f) + bias[lane];
    if constexpr (BN) {
        v = (v - mean[lane]) * rsqrtf(var[lane] + BN_EPS) * gamma[lane] + beta[lane];
        v = v > 0.f ? v : (__expf(v) - 1.f);   // ELU
    }
    if constexpr (FINAL) {
        float jk = fmaxf(x1[node * 64 + lane], v);
        const int o = (lane < 40) ? lane : 0;
        float dot = 0.f;
        #pragma unroll
        for (int c = 0; c < 64; ++c) {
            float jv = rl_f(jk, c);
            dot = fmaf(jv, sWf[c * 40 + o], dot);
        }
        float logit = (lane < 40) ? (dot + bf[o]) : -INFINITY;
        float mx = logit;
        #pragma unroll
        for (int mm = 1; mm < 64; mm <<= 1) mx = fmaxf(mx, __shfl_xor(mx, mm, 64));
        float ex = (lane < 40) ? __expf(logit - mx) : 0.f;
        float sum = ex;
        #pragma unroll
        for (int mm = 1; mm < 64; mm <<= 1) sum += __shfl_xor(sum, mm, 64);
        if (lane < 40) out40[node * 40 + lane] = logit - mx - logf(sum);
    } else {
        out[node * 64 + lane] = v;
    }
}

extern "C" void kernel_launch(void* const* d_in, const int* in_sizes, int n_in,
                              void* d_out, int out_size, void* d_ws, size_t ws_size,
                              hipStream_t stream) {
    const float* x     = (const float*)d_in[0];
    const int*   ei    = (const int*)d_in[1];
    const float* W1    = (const float*)d_in[2];
    const float* as1   = (const float*)d_in[3];
    const float* ad1   = (const float*)d_in[4];
    const float* b1    = (const float*)d_in[5];
    const float* gamma = (const float*)d_in[6];
    const float* beta  = (const float*)d_in[7];
    const float* mean  = (const float*)d_in[8];
    const float* var   = (const float*)d_in[9];
    const float* W2    = (const float*)d_in[10];
    const float* as2   = (const float*)d_in[11];
    const float* ad2   = (const float*)d_in[12];
    const float* b2    = (const float*)d_in[13];
    const float* Wf    = (const float*)d_in[14];
    const float* bf    = (const float*)d_in[15];
    float* out = (float*)d_out;
    const int* esrc = ei;
    const int* edst = ei + E_EDGES;

    char* ws = (char*)d_ws;
    size_t off = 0;
    auto alloc = [&](size_t bytes) {
        char* p = ws + off;
        off += (bytes + 255) & ~(size_t)255;
        return p;
    };
    unsigned* Ghist = (unsigned*)alloc((size_t)NSCAN * 4);
    unsigned* Goff  = (unsigned*)alloc((size_t)NSCAN * 4);
    int* partbase   = (int*)alloc((size_t)(P_PART + 1) * 4);
    unsigned* Gpart = (unsigned*)alloc((size_t)E_TOT * 4);
    int* ptr             = (int*)alloc((size_t)(N_NODES + 1) * 4);
    unsigned short* csr  = (unsigned short*)alloc((size_t)E_TOT * 2);
    __hip_bfloat16* hbuf = (__hip_bfloat16*)alloc((size_t)N_NODES * 64 * 2);
    float* x1buf = (float*)alloc((size_t)N_NODES * 64 * 4);
    float* asrc  = (float*)alloc((size_t)N_NODES * 2 * 4);
    float* adst  = (float*)alloc((size_t)N_NODES * 2 * 4);
    (void)ws_size; (void)in_sizes; (void)n_in; (void)out_size;

    const int NB = (N_NODES + 3) / 4;

    // ---------- CSR build (atomic-free partition sort) ----------
    hist_kernel<<<B1, 256, 0, stream>>>(edst, Ghist);
    scan2_kernel<<<1, 1024, 0, stream>>>(Ghist, Goff);
    partbase_kernel<<<1, 256, 0, stream>>>(Goff, partbase, ptr);
    scat2_kernel<<<B1, 256, 0, stream>>>(esrc, edst, Goff, Gpart);
    csr_kernel<<<P_PART, 256, 0, stream>>>(partbase, Gpart, ptr, csr);

    // ---------- layer 1 ----------
    lin_att_kernel<128><<<2048, 256, 0, stream>>>(x, W1, as1, ad1, hbuf, asrc, adst, N_NODES);
    gat_agg_kernel<true, false><<<NB, 256, 0, stream>>>(ptr, csr, hbuf,
        (const float2*)asrc, (const float2*)adst,
        b1, gamma, beta, mean, var, x1buf, nullptr, nullptr, nullptr, nullptr);

    // ---------- layer 2 (+ fused JK + final linear + log_softmax) ----------
    lin_att_kernel<64><<<2048, 256, 0, stream>>>(x1buf, W2, as2, ad2, hbuf, asrc, adst, N_NODES);
    gat_agg_kernel<false, true><<<NB, 256, 0, stream>>>(ptr, csr, hbuf,
        (const float2*)asrc, (const float2*)adst,
        b2, nullptr, nullptr, nullptr, nullptr, nullptr, x1buf, Wf, bf, out);
}